// Round 17
// baseline (236.963 us; speedup 1.0000x reference)
//
#include <hip/hip_runtime.h>
#include <hip/hip_bf16.h>

#define B_ 4
#define C_ 256
#define N_ 4096
#define LOG2E 1.4426950408889634f
#define THR_L2 11.5415603f   // 8 * log2(e), defer-max threshold in log2 domain

typedef unsigned short u16;
typedef __attribute__((ext_vector_type(4))) unsigned short u16x4;
typedef __attribute__((ext_vector_type(8))) short bf16x8;
typedef __attribute__((ext_vector_type(4))) float f32x4;
typedef __attribute__((ext_vector_type(2))) unsigned u32x2;
typedef __attribute__((ext_vector_type(4))) unsigned u32x4;

static __device__ __forceinline__ u16 f2bf(float f) {
    unsigned u = __float_as_uint(f);
    unsigned r = (u + 0x7FFFu + ((u >> 16) & 1u)) >> 16;
    return (u16)r;
}
static __device__ __forceinline__ float bf2f(u16 u) {
    return __uint_as_float(((unsigned)u) << 16);
}
static __device__ __forceinline__ float fexp2(float x) {   // native v_exp_f32 = 2^x
    float r; asm("v_exp_f32 %0, %1" : "=v"(r) : "v"(x)); return r;
}
static __device__ __forceinline__ unsigned cvt_pk_bf16(float lo, float hi) {
    unsigned r; asm("v_cvt_pk_bf16_f32 %0, %1, %2" : "=v"(r) : "v"(lo), "v"(hi)); return r;
}

static __device__ __forceinline__ f32x4 mfma16(bf16x8 a, bf16x8 b, f32x4 c) {
    return __builtin_amdgcn_mfma_f32_16x16x32_bf16(a, b, c, 0, 0, 0);
}

// Fragment-swizzled layouts (u16 offsets within one batch):
static __device__ __forceinline__ int swzQK(int row, int col) {
    return ((row >> 4) * 8 + (col >> 5)) * 512 + ((col >> 3) & 3) * 128 + (row & 15) * 8 + (col & 7);
}
static __device__ __forceinline__ int swzV(int d, int j) {
    return ((j >> 5) * 16 + (d >> 4)) * 512 + ((j >> 3) & 3) * 128 + (d & 15) * 8 + (j & 7);
}

typedef const __attribute__((address_space(1))) void* gas1_t;
typedef __attribute__((address_space(3))) void* las3_t;
static __device__ __forceinline__ void gll16(const u16* g, u16* l) {
    __builtin_amdgcn_global_load_lds((gas1_t)(const void*)g, (las3_t)(void*)l, 16, 0, 0);
}

// ---------------- kernel 1: weights f32 -> bf16 (K pre-scaled by log2e) ----------------
__global__ void wconv_kernel(const float* __restrict__ wq, const float* __restrict__ wk,
                             const float* __restrict__ wv,
                             u16* __restrict__ wqb, u16* __restrict__ wkb, u16* __restrict__ wvb) {
    int i = blockIdx.x * blockDim.x + threadIdx.x;
    wqb[i] = f2bf(wq[i]);
    wkb[i] = f2bf(wk[i] * LOG2E);
    wvb[i] = f2bf(wv[i]);
}

// ---------------- kernel 2: fused transpose + projections ----------------
__global__ __launch_bounds__(256) void proj_kernel(
    const float* __restrict__ pose,
    const u16* __restrict__ wqb, const float* __restrict__ bq,
    const u16* __restrict__ wkb, const float* __restrict__ bk,
    const u16* __restrict__ wvb, const float* __restrict__ bv,
    u16* __restrict__ Qm, u16* __restrict__ Km, u16* __restrict__ Vm)
{
    __shared__ __align__(16) u16 At[64][264];   // 33792 B

    int bid = blockIdx.x;              // B * N/64 = 256
    int b = bid >> 6;
    int n0 = (bid & 63) * 64;
    int tid = threadIdx.x;
    int lane = tid & 63;
    int wav = tid >> 6;
    int l15 = lane & 15, lg = lane >> 4;

    // in-kernel transpose: pose[c][n-slab] -> At[n][c] bf16
#pragma unroll
    for (int r = 0; r < 64; ++r) {
        int c = r * 4 + wav;
        float v = pose[(size_t)(b * C_ + c) * N_ + n0 + lane];
        At[lane][c] = f2bf(v);
    }
    __syncthreads();

    // ---- Q and K: wave owns 16 n-rows ----
    int nrow = n0 + wav * 16;
    bf16x8 afr[8];
#pragma unroll
    for (int kc = 0; kc < 8; ++kc)
        afr[kc] = *(const bf16x8*)(&At[wav * 16 + l15][kc * 32 + lg * 8]);

    for (int qk = 0; qk < 2; ++qk) {
        const u16* wb = qk ? wkb : wqb;
        const float* bias = qk ? bk : bq;
        u16* outm = qk ? Km : Qm;
        float bscale = qk ? LOG2E : 1.0f;
#pragma unroll
        for (int ct = 0; ct < 16; ++ct) {
            f32x4 acc = {0.f, 0.f, 0.f, 0.f};
            const u16* brow = wb + (size_t)(ct * 16 + l15) * C_;
#pragma unroll
            for (int kc = 0; kc < 8; ++kc) {
                bf16x8 bfr = *(const bf16x8*)(brow + kc * 32 + lg * 8);
                acc = mfma16(afr[kc], bfr, acc);
            }
            float bias_v = bias[ct * 16 + l15] * bscale;
#pragma unroll
            for (int reg = 0; reg < 4; ++reg) {
                int nr = nrow + lg * 4 + reg;
                outm[(size_t)b * N_ * C_ + swzQK(nr, ct * 16 + l15)] = f2bf(acc[reg] + bias_v);
            }
        }
    }

    // ---- V: wave owns 64 d-rows ----
    int d0w = wav * 64;
#pragma unroll
    for (int dt = 0; dt < 4; ++dt) {
        const u16* awrow = wvb + (size_t)(d0w + dt * 16 + l15) * C_;
        bf16x8 av[8];
#pragma unroll
        for (int kc = 0; kc < 8; ++kc)
            av[kc] = *(const bf16x8*)(awrow + kc * 32 + lg * 8);
#pragma unroll
        for (int nt = 0; nt < 4; ++nt) {
            f32x4 acc = {0.f, 0.f, 0.f, 0.f};
#pragma unroll
            for (int kc = 0; kc < 8; ++kc) {
                bf16x8 bfr = *(const bf16x8*)(&At[nt * 16 + l15][kc * 32 + lg * 8]);
                acc = mfma16(av[kc], bfr, acc);
            }
#pragma unroll
            for (int reg = 0; reg < 4; ++reg) {
                int dd = d0w + dt * 16 + lg * 4 + reg;
                Vm[(size_t)b * C_ * N_ + swzV(dd, n0 + nt * 16 + l15)] = f2bf(acc[reg] + bv[dd]);
            }
        }
    }
}

// ---------------- kernel 3: flash attention partial (i-split QK, d-split PV) ----------------
// 256 threads = 4 waves. QK: wave w computes P rows [w*16, w*16+16) x 64 j (as r13).
// P goes to a block-SHARED Plds[64][72]. PV: wave w computes ALL 64 i-rows for its
// 64-d slice -> V LDS reads drop 4x (8/wave-iter vs 32) and each A-frag feeds 4 MFMAs.
// Block-wide slow-path rescale via scale_s[64] + per-iter flag (defer-max keeps it rare).
// pO layout = accumulator-fragment order -> epilogue is 16 coalesced 8B stores, no LDS.
// K direct from global (L1/L2-shared); V single-buffered (staged at top, lands at mid
// barrier); Q staged once in LDS. l via ones-MFMA; log2-domain scores; cvt_pk P pack.
// NOTE: bare __launch_bounds__(256) only (r3/4/5/10/11: any hint => spill/sink).
// NOTE: NO s_setprio (r15: regresses lockstep structure). No LDS-pointer arrays (r8).
__global__ __launch_bounds__(256) void attn_partial_kernel(
    const u16* __restrict__ Qs, const u16* __restrict__ Ks, const u16* __restrict__ Vs,
    u16* __restrict__ pO, float* __restrict__ pM, float* __restrict__ pL,
    int S, int njt)
{
    __shared__ __align__(16) char smem[65536];       // Qlds 32KB | Vlds 32KB
    __shared__ __align__(16) u16 Plds[64][72];       // 9216 B, block-shared P
    __shared__ float scale_s[64];
    __shared__ unsigned flags[2];

    u16* Qlds = (u16*)smem;
    u16* Vlds = (u16*)(smem + 32768);

    int G = B_ * S;
    int bid = blockIdx.x;               // 64 * G
    int g = bid % G;                    // blocks with same g share a K/V slice
    int pos = bid / G;                  // 0..63 i-tile
    int b = g / S;
    int s = g % S;

    int tid = threadIdx.x;
    int lane = tid & 63;
    int w = tid >> 6;                   // QK: i-subtile; PV: d-chunk
    int l15 = lane & 15, lg = lane >> 4;

    const u16* Kbase = Ks + (size_t)b * N_ * C_;
    const u16* Vbase = Vs + (size_t)b * C_ * N_;
    int halfN = N_ / S;
    int jt_base16 = (s * halfN) >> 4;   // 16-row K granule index
    int jt_base32 = (s * halfN) >> 5;   // 32-col V granule index

    // prologue: stage Q tile (32KB, loop-invariant) then V tile 0 (32KB)
    {
        const u16* Qsrc = Qs + (size_t)b * N_ * C_ + (size_t)(pos * 4) * 4096;
#pragma unroll
        for (int q = 0; q < 8; ++q) {
            int v = q * 256 + tid;
            gll16(Qsrc + v * 8, Qlds + v * 8);
        }
        const u16* Vsrc = Vbase + (size_t)jt_base32 * 8192;
#pragma unroll
        for (int q = 0; q < 8; ++q) {
            int v = q * 256 + tid;
            gll16(Vsrc + v * 8, Vlds + v * 8);
        }
    }
    if (tid < 2) flags[tid] = 0;

    bf16x8 b_ones;
#pragma unroll
    for (int e = 0; e < 8; ++e) b_ones[e] = (short)0x3F80;   // bf16 1.0

    f32x4 Ot[16];                       // [it*4+dt]: rows i=it*16+lg*4+reg, col d=w*64+dt*16+l15
#pragma unroll
    for (int t = 0; t < 16; ++t) Ot[t] = (f32x4){0.f, 0.f, 0.f, 0.f};
    f32x4 Lacc = {0.f, 0.f, 0.f, 0.f};
    float m_r[4] = {-1e30f, -1e30f, -1e30f, -1e30f};

    const u16* q_lds = Qlds + w * 4096 + lane * 8;   // + kc*512

    __syncthreads();   // Q, V(0), flags ready

    for (int jt = 0; jt < njt; ++jt) {
        if (tid == 0) flags[(jt + 1) & 1] = 0;   // reset slot consumed at jt-1

        if (jt > 0) {   // stage V(jt): buffer free (all waves past end barrier of jt-1)
            const u16* Vsrc = Vbase + (size_t)(jt_base32 + jt * 2) * 8192;
#pragma unroll
            for (int q = 0; q < 8; ++q) {
                int v = q * 256 + tid;
                gll16(Vsrc + v * 8, Vlds + v * 8);
            }
        }

        // QK^T: 4 interleaved chains, K direct from global, Q from LDS
        const u16* Ksrc = Kbase + (size_t)(jt_base16 + jt * 4) * 4096 + lane * 8;
        f32x4 sc[4];
#pragma unroll
        for (int t = 0; t < 4; ++t) sc[t] = (f32x4){0.f, 0.f, 0.f, 0.f};
#pragma unroll
        for (int kc = 0; kc < 8; ++kc) {
            bf16x8 qv = *(const bf16x8*)(q_lds + kc * 512);
#pragma unroll
            for (int t = 0; t < 4; ++t) {
                bf16x8 kf = *(const bf16x8*)(Ksrc + (t * 8 + kc) * 512);
                sc[t] = mfma16(qv, kf, sc[t]);
            }
        }

        // defer-max check (per QK wave)
        float scale_r[4] = {1.f, 1.f, 1.f, 1.f};
        bool ok = true;
#pragma unroll
        for (int reg = 0; reg < 4; ++reg) {
            float lim = m_r[reg] + THR_L2;
#pragma unroll
            for (int t = 0; t < 4; ++t) ok = ok && (sc[t][reg] <= lim);
        }
        if (!__all(ok)) {
            // slow path: full row-max reduce; rescale L now, publish scale for Ot
#pragma unroll
            for (int reg = 0; reg < 4; ++reg) {
                float rm = fmaxf(fmaxf(sc[0][reg], sc[1][reg]), fmaxf(sc[2][reg], sc[3][reg]));
                rm = fmaxf(rm, __shfl_xor(rm, 1));
                rm = fmaxf(rm, __shfl_xor(rm, 2));
                rm = fmaxf(rm, __shfl_xor(rm, 4));
                rm = fmaxf(rm, __shfl_xor(rm, 8));
                float mn = fmaxf(m_r[reg], rm);
                float scale = fexp2(m_r[reg] - mn);
                m_r[reg] = mn;
                Lacc[reg] *= scale;
                scale_r[reg] = scale;
            }
            if (lane == 0) flags[jt & 1] = 1;
        }
        if (l15 == 0) {
#pragma unroll
            for (int reg = 0; reg < 4; ++reg)
                scale_s[w * 16 + lg * 4 + reg] = scale_r[reg];
        }

        // P = 2^(s - m) -> bf16 (cvt_pk) -> shared Plds (global rows)
#pragma unroll
        for (int reg = 0; reg < 4; ++reg) {
            float m = m_r[reg];
            int row = w * 16 + lg * 4 + reg;
            unsigned pk01 = cvt_pk_bf16(fexp2(sc[0][reg] - m), fexp2(sc[1][reg] - m));
            unsigned pk23 = cvt_pk_bf16(fexp2(sc[2][reg] - m), fexp2(sc[3][reg] - m));
            Plds[row][l15]      = (u16)pk01;
            Plds[row][16 + l15] = (u16)(pk01 >> 16);
            Plds[row][32 + l15] = (u16)pk23;
            Plds[row][48 + l15] = (u16)(pk23 >> 16);
        }

        __syncthreads();   // mid: P complete + V(jt) landed (vmcnt drain)

        // block-wide deferred O-rescale (rare)
        if (flags[jt & 1] != 0) {
#pragma unroll
            for (int it = 0; it < 4; ++it) {
                int ib = it * 16 + lg * 4;
                float s0 = scale_s[ib + 0], s1 = scale_s[ib + 1];
                float s2 = scale_s[ib + 2], s3 = scale_s[ib + 3];
#pragma unroll
                for (int dt = 0; dt < 4; ++dt) {
                    Ot[it * 4 + dt][0] *= s0;
                    Ot[it * 4 + dt][1] *= s1;
                    Ot[it * 4 + dt][2] *= s2;
                    Ot[it * 4 + dt][3] *= s3;
                }
            }
        }

        // PV d-split: hoisted V fragments for this wave's 64-d slice
        bf16x8 vf0[4], vf1[4];
#pragma unroll
        for (int dt = 0; dt < 4; ++dt) {
            vf0[dt] = *(const bf16x8*)(Vlds + (w * 4 + dt) * 512 + lane * 8);
            vf1[dt] = *(const bf16x8*)(Vlds + 8192 + (w * 4 + dt) * 512 + lane * 8);
        }
#pragma unroll
        for (int it = 0; it < 4; ++it) {
            bf16x8 af0 = *(const bf16x8*)(&Plds[it * 16 + l15][lg * 8]);
            bf16x8 af1 = *(const bf16x8*)(&Plds[it * 16 + l15][32 + lg * 8]);
            if (it == w) {   // row-sum for this wave's own QK rows
                Lacc = mfma16(af0, b_ones, Lacc);
                Lacc = mfma16(af1, b_ones, Lacc);
            }
#pragma unroll
            for (int dt = 0; dt < 4; ++dt) {
                Ot[it * 4 + dt] = mfma16(af0, vf0[dt], Ot[it * 4 + dt]);
                Ot[it * 4 + dt] = mfma16(af1, vf1[dt], Ot[it * 4 + dt]);
            }
        }

        __syncthreads();   // end: all waves done reading Vlds/Plds (safe to restage)
    }

    // ---- epilogue: m/L per QK-wave rows; O as coalesced 8B fragment stores ----
    size_t rowb = (size_t)(s * B_ + b) * N_ + pos * 64 + w * 16;
    if (l15 == 0) {
#pragma unroll
        for (int reg = 0; reg < 4; ++reg) {
            pM[rowb + lg * 4 + reg] = m_r[reg];
            pL[rowb + lg * 4 + reg] = Lacc[reg];
        }
    }
    // pO layout: (((s*B+b)*64 + pos) * 16384) + dchunk*4096 + (it*4+dt)*256 + lane*4 + reg
    size_t obase = (((size_t)(s * B_ + b) * 64 + pos) << 14) + (size_t)w * 4096;
#pragma unroll
    for (int t = 0; t < 16; ++t) {
        u32x2 pk;
        pk[0] = cvt_pk_bf16(Ot[t][0], Ot[t][1]);
        pk[1] = cvt_pk_bf16(Ot[t][2], Ot[t][3]);
        *(u32x2*)(pO + obase + t * 256 + lane * 4) = pk;
    }
}

// ---------------- kernel 4: combine partials + residual (log2-domain m) ----------------
// Reads pO in the attn fragment layout with contiguous u16x4 loads.
__global__ __launch_bounds__(256) void combine_kernel(
    const u16* __restrict__ pO, const float* __restrict__ pM, const float* __restrict__ pL,
    const float* __restrict__ pose, const float* __restrict__ gamma_p,
    float* __restrict__ out, int S)
{
    __shared__ float a_s[4][64];
    __shared__ float tile[64][65];

    int bid = blockIdx.x;              // B*4*64 = 1024
    int b = bid >> 8;
    int ct = (bid >> 6) & 3;           // d-chunk
    int ipos = bid & 63;               // i-tile
    int c0 = ct * 64, i0 = ipos * 64;
    int tid = threadIdx.x;

    if (tid < 64) {
        int i = i0 + tid;
        float M = -1e30f;
        for (int s = 0; s < S; ++s)
            M = fmaxf(M, pM[(size_t)(s * B_ + b) * N_ + i]);
        float L = 0.f;
        for (int s = 0; s < S; ++s) {
            size_t idx = (size_t)(s * B_ + b) * N_ + i;
            L += pL[idx] * fexp2(pM[idx] - M);
        }
        float invL = 1.0f / L;
        for (int s = 0; s < S; ++s) {
            size_t idx = (size_t)(s * B_ + b) * N_ + i;
            a_s[s][tid] = fexp2(pM[idx] - M) * invL;
        }
    }
    __syncthreads();

    int dt = tid >> 6, lane = tid & 63, lg = lane >> 4, l15 = lane & 15;
    int dl = dt * 16 + l15;
#pragma unroll
    for (int it = 0; it < 4; ++it) {
        float acc0 = 0.f, acc1 = 0.f, acc2 = 0.f, acc3 = 0.f;
        int ib = it * 16 + lg * 4;
        for (int s = 0; s < S; ++s) {
            size_t base = (((size_t)(s * B_ + b) * 64 + ipos) << 14) + ct * 4096
                        + (it * 4 + dt) * 256 + lane * 4;
            u16x4 u = *(const u16x4*)(pO + base);
            acc0 += a_s[s][ib + 0] * bf2f(u[0]);
            acc1 += a_s[s][ib + 1] * bf2f(u[1]);
            acc2 += a_s[s][ib + 2] * bf2f(u[2]);
            acc3 += a_s[s][ib + 3] * bf2f(u[3]);
        }
        tile[ib + 0][dl] = acc0;
        tile[ib + 1][dl] = acc1;
        tile[ib + 2][dl] = acc2;
        tile[ib + 3][dl] = acc3;
    }
    __syncthreads();

    float g = gamma_p[0];
    int lane2 = tid & 63, hi = tid >> 6;
#pragma unroll
    for (int r = 0; r < 16; ++r) {
        int cc = r * 4 + hi;
        size_t addr = (size_t)(b * C_ + c0 + cc) * N_ + i0 + lane2;
        out[addr] = pose[addr] + g * tile[lane2][cc];
    }
}

extern "C" void kernel_launch(void* const* d_in, const int* in_sizes, int n_in,
                              void* d_out, int out_size, void* d_ws, size_t ws_size,
                              hipStream_t stream) {
    (void)in_sizes; (void)n_in; (void)out_size; (void)ws_size;
    const float* pose = (const float*)d_in[0];
    const float* wq = (const float*)d_in[1];
    const float* bq = (const float*)d_in[2];
    const float* wk = (const float*)d_in[3];
    const float* bk = (const float*)d_in[4];
    const float* wv = (const float*)d_in[5];
    const float* bv = (const float*)d_in[6];
    const float* gamma = (const float*)d_in[7];
    float* out = (float*)d_out;

    const int S = 2;   // global j-split
    char* ws = (char*)d_ws;
    u16* wqb   = (u16*)(ws + 0);
    u16* wkb   = (u16*)(ws + (128 << 10));
    u16* wvb   = (u16*)(ws + (256 << 10));
    float* pM  = (float*)(ws + (384 << 10));
    float* pL  = pM + (size_t)S * B_ * N_;
    u16* Qm    = (u16*)(ws + (1 << 20));     // 8 MB (swizzled)
    u16* Km    = (u16*)(ws + (9 << 20));     // 8 MB (swizzled, log2e-scaled)
    u16* Vm    = (u16*)(ws + (17 << 20));    // 8 MB (swizzled)
    u16* pO    = (u16*)(ws + (25 << 20));    // S*8 MB (fragment layout)

    int njt = (N_ / S) / 64;

    hipLaunchKernelGGL(wconv_kernel, dim3(256), dim3(256), 0, stream, wq, wk, wv, wqb, wkb, wvb);
    hipLaunchKernelGGL(proj_kernel, dim3(256), dim3(256), 0, stream,
                       pose, wqb, bq, wkb, bk, wvb, bv, Qm, Km, Vm);
    hipLaunchKernelGGL(attn_partial_kernel, dim3(64 * B_ * S), dim3(256), 0, stream,
                       Qm, Km, Vm, pO, pM, pL, S, njt);
    hipLaunchKernelGGL(combine_kernel, dim3(1024), dim3(256), 0, stream,
                       pO, pM, pL, pose, gamma, out, S);
}

// Round 18
// 204.345 us; speedup vs baseline: 1.1596x; 1.1596x over previous
//
#include <hip/hip_runtime.h>
#include <hip/hip_bf16.h>

#define B_ 4
#define C_ 256
#define N_ 4096
#define LOG2E 1.4426950408889634f
#define THR_L2 11.5415603f   // 8 * log2(e), defer-max threshold in log2 domain

typedef unsigned short u16;
typedef __attribute__((ext_vector_type(4))) unsigned short u16x4;
typedef __attribute__((ext_vector_type(8))) short bf16x8;
typedef __attribute__((ext_vector_type(4))) float f32x4;
typedef __attribute__((ext_vector_type(4))) unsigned u32x4;

static __device__ __forceinline__ u16 f2bf(float f) {
    unsigned u = __float_as_uint(f);
    unsigned r = (u + 0x7FFFu + ((u >> 16) & 1u)) >> 16;
    return (u16)r;
}
static __device__ __forceinline__ float bf2f(u16 u) {
    return __uint_as_float(((unsigned)u) << 16);
}
static __device__ __forceinline__ float fexp2(float x) {   // native v_exp_f32 = 2^x
    float r; asm("v_exp_f32 %0, %1" : "=v"(r) : "v"(x)); return r;
}
static __device__ __forceinline__ unsigned cvt_pk_bf16(float lo, float hi) {
    unsigned r; asm("v_cvt_pk_bf16_f32 %0, %1, %2" : "=v"(r) : "v"(lo), "v"(hi)); return r;
}

static __device__ __forceinline__ f32x4 mfma16(bf16x8 a, bf16x8 b, f32x4 c) {
    return __builtin_amdgcn_mfma_f32_16x16x32_bf16(a, b, c, 0, 0, 0);
}

// Fragment-swizzled layouts (u16 offsets within one batch):
static __device__ __forceinline__ int swzQK(int row, int col) {
    return ((row >> 4) * 8 + (col >> 5)) * 512 + ((col >> 3) & 3) * 128 + (row & 15) * 8 + (col & 7);
}
static __device__ __forceinline__ int swzV(int d, int j) {
    return ((j >> 5) * 16 + (d >> 4)) * 512 + ((j >> 3) & 3) * 128 + (d & 15) * 8 + (j & 7);
}

typedef const __attribute__((address_space(1))) void* gas1_t;
typedef __attribute__((address_space(3))) void* las3_t;
static __device__ __forceinline__ void gll16(const u16* g, u16* l) {
    __builtin_amdgcn_global_load_lds((gas1_t)(const void*)g, (las3_t)(void*)l, 16, 0, 0);
}

// ---------------- kernel 1: weights f32 -> bf16 (K pre-scaled by log2e) ----------------
__global__ void wconv_kernel(const float* __restrict__ wq, const float* __restrict__ wk,
                             const float* __restrict__ wv,
                             u16* __restrict__ wqb, u16* __restrict__ wkb, u16* __restrict__ wvb) {
    int i = blockIdx.x * blockDim.x + threadIdx.x;
    wqb[i] = f2bf(wq[i]);
    wkb[i] = f2bf(wk[i] * LOG2E);
    wvb[i] = f2bf(wv[i]);
}

// ---------------- kernel 2: fused transpose + projections ----------------
// Reads pose [B,C,N] f32 directly; transposes its 64-n slab into an LDS bf16
// tile [64 n][264 c] (2-way bank pattern, free); GEMM fragments read from LDS.
// Outputs Q/K/V in fragment-swizzled layouts (K log2e-scaled).
__global__ __launch_bounds__(256) void proj_kernel(
    const float* __restrict__ pose,
    const u16* __restrict__ wqb, const float* __restrict__ bq,
    const u16* __restrict__ wkb, const float* __restrict__ bk,
    const u16* __restrict__ wvb, const float* __restrict__ bv,
    u16* __restrict__ Qm, u16* __restrict__ Km, u16* __restrict__ Vm)
{
    __shared__ __align__(16) u16 At[64][264];   // 33792 B

    int bid = blockIdx.x;              // B * N/64 = 256
    int b = bid >> 6;
    int n0 = (bid & 63) * 64;
    int tid = threadIdx.x;
    int lane = tid & 63;
    int wav = tid >> 6;
    int l15 = lane & 15, lg = lane >> 4;

    // in-kernel transpose: pose[c][n-slab] -> At[n][c] bf16
#pragma unroll
    for (int r = 0; r < 64; ++r) {
        int c = r * 4 + wav;
        float v = pose[(size_t)(b * C_ + c) * N_ + n0 + lane];
        At[lane][c] = f2bf(v);
    }
    __syncthreads();

    // ---- Q and K: wave owns 16 n-rows ----
    int nrow = n0 + wav * 16;
    bf16x8 afr[8];
#pragma unroll
    for (int kc = 0; kc < 8; ++kc)
        afr[kc] = *(const bf16x8*)(&At[wav * 16 + l15][kc * 32 + lg * 8]);

    for (int qk = 0; qk < 2; ++qk) {
        const u16* wb = qk ? wkb : wqb;
        const float* bias = qk ? bk : bq;
        u16* outm = qk ? Km : Qm;
        float bscale = qk ? LOG2E : 1.0f;
#pragma unroll
        for (int ct = 0; ct < 16; ++ct) {
            f32x4 acc = {0.f, 0.f, 0.f, 0.f};
            const u16* brow = wb + (size_t)(ct * 16 + l15) * C_;
#pragma unroll
            for (int kc = 0; kc < 8; ++kc) {
                bf16x8 bfr = *(const bf16x8*)(brow + kc * 32 + lg * 8);
                acc = mfma16(afr[kc], bfr, acc);
            }
            float bias_v = bias[ct * 16 + l15] * bscale;
#pragma unroll
            for (int reg = 0; reg < 4; ++reg) {
                int nr = nrow + lg * 4 + reg;
                outm[(size_t)b * N_ * C_ + swzQK(nr, ct * 16 + l15)] = f2bf(acc[reg] + bias_v);
            }
        }
    }

    // ---- V: wave owns 64 d-rows ----
    int d0w = wav * 64;
#pragma unroll
    for (int dt = 0; dt < 4; ++dt) {
        const u16* awrow = wvb + (size_t)(d0w + dt * 16 + l15) * C_;
        bf16x8 av[8];
#pragma unroll
        for (int kc = 0; kc < 8; ++kc)
            av[kc] = *(const bf16x8*)(awrow + kc * 32 + lg * 8);
#pragma unroll
        for (int nt = 0; nt < 4; ++nt) {
            f32x4 acc = {0.f, 0.f, 0.f, 0.f};
#pragma unroll
            for (int kc = 0; kc < 8; ++kc) {
                bf16x8 bfr = *(const bf16x8*)(&At[nt * 16 + l15][kc * 32 + lg * 8]);
                acc = mfma16(av[kc], bfr, acc);
            }
#pragma unroll
            for (int reg = 0; reg < 4; ++reg) {
                int dd = d0w + dt * 16 + lg * 4 + reg;
                Vm[(size_t)b * C_ * N_ + swzV(dd, n0 + nt * 16 + l15)] = f2bf(acc[reg] + bv[dd]);
            }
        }
    }
}

// ---------------- kernel 3: flash attention partial (exact r13 body, KBLK=64) ----------------
// 256 threads = 4 waves x 16 i-rows (64-row i-tile). Per iteration: 64 j.
// Q staged ONCE in LDS; K direct from global (L1-shared, depth-1 per kc);
// V single-buffered in LDS (staged at top, landed at mid barrier).
// Defer-max; l via ones-MFMA; log2-domain scores; cvt_pk P pack.
// NOTE: bare __launch_bounds__(256) only (r3/4/5/10/11: any hint => spill/sink).
// NOTE: NO s_setprio — r15 proved it regresses this barrier-lockstep structure
// (137 -> 159 us; T5 needs wave role diversity which this kernel lacks).
// NOTE: per-wave Plds (r17: block-shared P doubles bank conflicts, -20%).
// NOTE: no arrays of LDS-derived pointers (r8 compile fail).
__global__ __launch_bounds__(256) void attn_partial_kernel(
    const u16* __restrict__ Qs, const u16* __restrict__ Ks, const u16* __restrict__ Vs,
    u16* __restrict__ pO, float* __restrict__ pM, float* __restrict__ pL,
    int S, int njt)
{
    __shared__ __align__(16) char smem[65536];       // Qlds 32KB | Vlds 32KB ; obuf aliases Qlds
    __shared__ __align__(16) u16 Plds[4][16][72];    // 9216 B

    u16* Qlds = (u16*)smem;
    u16* Vlds = (u16*)(smem + 32768);

    int G = B_ * S;
    int bid = blockIdx.x;               // 64 * G
    int g = bid % G;                    // blocks with same g share a K/V slice
    int pos = bid / G;                  // 0..63 i-tile
    int b = g / S;
    int s = g % S;
    int i0 = pos * 64;

    int tid = threadIdx.x;
    int lane = tid & 63;
    int w = tid >> 6;                   // i-subtile 0..3
    int l15 = lane & 15, lg = lane >> 4;

    const u16* Kbase = Ks + (size_t)b * N_ * C_;
    const u16* Vbase = Vs + (size_t)b * C_ * N_;
    int halfN = N_ / S;
    int jt_base16 = (s * halfN) >> 4;   // 16-row K granule index
    int jt_base32 = (s * halfN) >> 5;   // 32-col V granule index

    // prologue: stage Q tile (32KB, loop-invariant) then V tile 0 (32KB)
    {
        const u16* Qsrc = Qs + (size_t)b * N_ * C_ + (size_t)(pos * 4) * 4096;
#pragma unroll
        for (int q = 0; q < 8; ++q) {
            int v = q * 256 + tid;
            gll16(Qsrc + v * 8, Qlds + v * 8);
        }
        const u16* Vsrc = Vbase + (size_t)jt_base32 * 8192;
#pragma unroll
        for (int q = 0; q < 8; ++q) {
            int v = q * 256 + tid;
            gll16(Vsrc + v * 8, Vlds + v * 8);
        }
    }

    bf16x8 b_ones;
#pragma unroll
    for (int e = 0; e < 8; ++e) b_ones[e] = (short)0x3F80;   // bf16 1.0

    f32x4 Ot[16];
#pragma unroll
    for (int ct = 0; ct < 16; ++ct) Ot[ct] = (f32x4){0.f, 0.f, 0.f, 0.f};
    f32x4 Lacc = {0.f, 0.f, 0.f, 0.f};
    float m_r[4] = {-1e30f, -1e30f, -1e30f, -1e30f};

    const u16* q_lds = Qlds + w * 4096 + lane * 8;   // + kc*512

    __syncthreads();   // Q and V(0) landed

    for (int jt = 0; jt < njt; ++jt) {
        if (jt > 0) {   // stage V(jt): buffer free (all waves past PV(jt-1) barrier)
            const u16* Vsrc = Vbase + (size_t)(jt_base32 + jt * 2) * 8192;
#pragma unroll
            for (int q = 0; q < 8; ++q) {
                int v = q * 256 + tid;
                gll16(Vsrc + v * 8, Vlds + v * 8);
            }
        }

        // QK^T: 4 interleaved chains, K direct from global, Q from LDS
        const u16* Ksrc = Kbase + (size_t)(jt_base16 + jt * 4) * 4096 + lane * 8;
        f32x4 sc[4];
#pragma unroll
        for (int t = 0; t < 4; ++t) sc[t] = (f32x4){0.f, 0.f, 0.f, 0.f};
#pragma unroll
        for (int kc = 0; kc < 8; ++kc) {
            bf16x8 qv = *(const bf16x8*)(q_lds + kc * 512);
#pragma unroll
            for (int t = 0; t < 4; ++t) {
                bf16x8 kf = *(const bf16x8*)(Ksrc + (t * 8 + kc) * 512);
                sc[t] = mfma16(qv, kf, sc[t]);
            }
        }

        // defer-max check (wave-uniform)
        bool ok = true;
#pragma unroll
        for (int reg = 0; reg < 4; ++reg) {
            float lim = m_r[reg] + THR_L2;
#pragma unroll
            for (int t = 0; t < 4; ++t) ok = ok && (sc[t][reg] <= lim);
        }
        if (!__all(ok)) {
            // slow path: full row-max reduce + rescale O and L
#pragma unroll
            for (int reg = 0; reg < 4; ++reg) {
                float rm = fmaxf(fmaxf(sc[0][reg], sc[1][reg]), fmaxf(sc[2][reg], sc[3][reg]));
                rm = fmaxf(rm, __shfl_xor(rm, 1));
                rm = fmaxf(rm, __shfl_xor(rm, 2));
                rm = fmaxf(rm, __shfl_xor(rm, 4));
                rm = fmaxf(rm, __shfl_xor(rm, 8));
                float mn = fmaxf(m_r[reg], rm);
                float scale = fexp2(m_r[reg] - mn);
                m_r[reg] = mn;
                Lacc[reg] *= scale;
#pragma unroll
                for (int ct = 0; ct < 16; ++ct) Ot[ct][reg] *= scale;
            }
        }

        // P = 2^(s - m) -> bf16 (cvt_pk) -> Plds
#pragma unroll
        for (int reg = 0; reg < 4; ++reg) {
            float m = m_r[reg];
            unsigned pk01 = cvt_pk_bf16(fexp2(sc[0][reg] - m), fexp2(sc[1][reg] - m));
            unsigned pk23 = cvt_pk_bf16(fexp2(sc[2][reg] - m), fexp2(sc[3][reg] - m));
            Plds[w][lg * 4 + reg][l15]      = (u16)pk01;
            Plds[w][lg * 4 + reg][16 + l15] = (u16)(pk01 >> 16);
            Plds[w][lg * 4 + reg][32 + l15] = (u16)pk23;
            Plds[w][lg * 4 + reg][48 + l15] = (u16)(pk23 >> 16);
        }

        __syncthreads();   // V(jt) landed (vmcnt drain) + all waves synced

        bf16x8 af0 = *(const bf16x8*)(&Plds[w][l15][lg * 8]);
        bf16x8 af1 = *(const bf16x8*)(&Plds[w][l15][32 + lg * 8]);
        Lacc = mfma16(af0, b_ones, Lacc);
        Lacc = mfma16(af1, b_ones, Lacc);

        // PV: 32 MFMAs over 16 independent Ot chains
#pragma unroll
        for (int ct = 0; ct < 16; ++ct) {
            bf16x8 vf0 = *(const bf16x8*)(Vlds + ct * 512 + lane * 8);
            bf16x8 vf1 = *(const bf16x8*)(Vlds + 8192 + ct * 512 + lane * 8);
            Ot[ct] = mfma16(af0, vf0, Ot[ct]);
            Ot[ct] = mfma16(af1, vf1, Ot[ct]);
        }

        __syncthreads();   // all waves done reading Vlds (safe to restage)
    }

    // ---- epilogue ----
    size_t rowb = (size_t)(s * B_ + b) * N_ + i0 + w * 16;
    if (l15 == 0) {
#pragma unroll
        for (int reg = 0; reg < 4; ++reg) {
            pM[rowb + lg * 4 + reg] = m_r[reg];
            pL[rowb + lg * 4 + reg] = Lacc[reg];
        }
    }
    float* obuf = (float*)smem;   // [64][66], aliases Qlds (done with Q)
    size_t prow = (size_t)(s * B_ + b) * N_ + i0;
#pragma unroll
    for (int cc = 0; cc < 4; ++cc) {
#pragma unroll
        for (int u = 0; u < 4; ++u)
#pragma unroll
            for (int reg = 0; reg < 4; ++reg)
                obuf[(w * 16 + lg * 4 + reg) * 66 + u * 16 + l15] = Ot[cc * 4 + u][reg];
        __syncthreads();
#pragma unroll
        for (int h = 0; h < 2; ++h) {
            int v = h * 256 + tid;
            int row = v >> 3, cg = v & 7;
            const float* src = obuf + row * 66 + cg * 8;
            u32x4 pk;
#pragma unroll
            for (int k = 0; k < 4; ++k)
                pk[k] = (unsigned)f2bf(src[2 * k]) | ((unsigned)f2bf(src[2 * k + 1]) << 16);
            *(u32x4*)(pO + (prow + row) * C_ + cc * 64 + cg * 8) = pk;
        }
        __syncthreads();
    }
}

// ---------------- kernel 4: combine partials + residual (log2-domain m) ----------------
__global__ __launch_bounds__(256) void combine_kernel(
    const u16* __restrict__ pO, const float* __restrict__ pM, const float* __restrict__ pL,
    const float* __restrict__ pose, const float* __restrict__ gamma_p,
    float* __restrict__ out, int S)
{
    __shared__ float a_s[4][64];
    __shared__ float tile[64][65];

    int bid = blockIdx.x;              // B*4*64 = 1024
    int b = bid >> 8;
    int ct = (bid >> 6) & 3;
    int it = bid & 63;
    int c0 = ct * 64, i0 = it * 64;
    int tid = threadIdx.x;

    if (tid < 64) {
        int i = i0 + tid;
        float M = -1e30f;
        for (int s = 0; s < S; ++s)
            M = fmaxf(M, pM[(size_t)(s * B_ + b) * N_ + i]);
        float L = 0.f;
        for (int s = 0; s < S; ++s) {
            size_t idx = (size_t)(s * B_ + b) * N_ + i;
            L += pL[idx] * fexp2(pM[idx] - M);
        }
        float invL = 1.0f / L;
        for (int s = 0; s < S; ++s) {
            size_t idx = (size_t)(s * B_ + b) * N_ + i;
            a_s[s][tid] = fexp2(pM[idx] - M) * invL;
        }
    }
    __syncthreads();

    // vectorized pO accumulate: 16 threads per i-row, ushort4 (8B) per thread
    int cq = (tid & 15) * 4;
#pragma unroll
    for (int rr = 0; rr < 4; ++rr) {
        int il = rr * 16 + (tid >> 4);
        float acc0 = 0.f, acc1 = 0.f, acc2 = 0.f, acc3 = 0.f;
        for (int s = 0; s < S; ++s) {
            size_t base = ((size_t)(s * B_ + b) * N_ + i0 + il) * C_ + c0 + cq;
            u16x4 u = *(const u16x4*)(pO + base);
            float a = a_s[s][il];
            acc0 += a * bf2f(u[0]);
            acc1 += a * bf2f(u[1]);
            acc2 += a * bf2f(u[2]);
            acc3 += a * bf2f(u[3]);
        }
        tile[il][cq]     = acc0;
        tile[il][cq + 1] = acc1;
        tile[il][cq + 2] = acc2;
        tile[il][cq + 3] = acc3;
    }
    __syncthreads();

    float g = gamma_p[0];
    int lane = tid & 63, hi = tid >> 6;
#pragma unroll
    for (int r = 0; r < 16; ++r) {
        int cc = r * 4 + hi;
        size_t addr = (size_t)(b * C_ + c0 + cc) * N_ + i0 + lane;
        out[addr] = pose[addr] + g * tile[lane][cc];
    }
}

extern "C" void kernel_launch(void* const* d_in, const int* in_sizes, int n_in,
                              void* d_out, int out_size, void* d_ws, size_t ws_size,
                              hipStream_t stream) {
    (void)in_sizes; (void)n_in; (void)out_size; (void)ws_size;
    const float* pose = (const float*)d_in[0];
    const float* wq = (const float*)d_in[1];
    const float* bq = (const float*)d_in[2];
    const float* wk = (const float*)d_in[3];
    const float* bk = (const float*)d_in[4];
    const float* wv = (const float*)d_in[5];
    const float* bv = (const float*)d_in[6];
    const float* gamma = (const float*)d_in[7];
    float* out = (float*)d_out;

    const int S = 2;   // global j-split
    char* ws = (char*)d_ws;
    u16* wqb   = (u16*)(ws + 0);
    u16* wkb   = (u16*)(ws + (128 << 10));
    u16* wvb   = (u16*)(ws + (256 << 10));
    float* pM  = (float*)(ws + (384 << 10));
    float* pL  = pM + (size_t)S * B_ * N_;
    u16* Qm    = (u16*)(ws + (1 << 20));     // 8 MB (swizzled)
    u16* Km    = (u16*)(ws + (9 << 20));     // 8 MB (swizzled, log2e-scaled)
    u16* Vm    = (u16*)(ws + (17 << 20));    // 8 MB (swizzled)
    u16* pO    = (u16*)(ws + (25 << 20));    // S*8 MB

    int njt = (N_ / S) / 64;

    hipLaunchKernelGGL(wconv_kernel, dim3(256), dim3(256), 0, stream, wq, wk, wv, wqb, wkb, wvb);
    hipLaunchKernelGGL(proj_kernel, dim3(256), dim3(256), 0, stream,
                       pose, wqb, bq, wkb, bk, wvb, bv, Qm, Km, Vm);
    hipLaunchKernelGGL(attn_partial_kernel, dim3(64 * B_ * S), dim3(256), 0, stream,
                       Qm, Km, Vm, pO, pM, pL, S, njt);
    hipLaunchKernelGGL(combine_kernel, dim3(1024), dim3(256), 0, stream,
                       pO, pM, pL, pose, gamma, out, S);
}